// Round 11
// baseline (276.737 us; speedup 1.0000x reference)
//
#include <hip/hip_runtime.h>

// InnerShiftTriple: bz=4, c=512 (c2=256), h=w=64 (hw=4096), fp32 in/out, int32 mask.
// out = concat([former, latter, shifted]); shifted[i] = former[argmax_j sim(i,j)]
// for masked i over non-masked keys j, cosine sim of "latter" features.
// Argmax invariant to query normalization -> only keys normalized.
//
// Pass1: TQ=32 x 512-key items, 4-wave blocks, launch_bounds(256,4) (register
// footprint ~112/thread incl AGPR-held acc -> 4 waves/SIMD cap -> 1024 slots).
// R8-R10 lesson arc: items totalled ~1152 because kc>2048 spawns a 5th slice
// with ~30 real keys -> ~128 nearly-empty full-cost items -> forced 60us tail;
// three attempts to speed the tail's EXECUTION failed (R9 SMEM s_load is
// out-of-order -> lgkmcnt(0) drains; R10 LDS-q bloated VGPR 48->64).
// THIS ROUND: delete the tail's work instead. Main slices capped at 4
// (total_main ~= 1024 = slot capacity); overflow keys [2048,kc) are extra
// work ids in the SAME phase-1 loop / SAME run_item<32> call site (kpack is
// zero-padded, kk<kc guards, partials has 8 slice slots, pass2 already reads
// them). Idle blocks grab overflow during the main round. Bit-identical.
// Fused passthrough copy kept (R8: free; pass1 WRITE_SIZE 33MB == copy).

#define HW 4096
#define C2 256
#define BZd 4
#define TQ 32         // queries per full work item (SGPR-broadcast)
#define NK 2          // keys per thread (one float2)
#define BT 256        // pass1 block = 4 waves; block covers BT*NK = 512 keys
#define SLK 512       // keys per slice
#define NSL_MAX 8     // up to 8 slices of 512 keys
#define QT_MAX 128    // HW/TQ
#define P1_GRID 1024  // exactly the resident capacity at 4 blocks/CU
#define CP_GRID 2048  // appended passthrough-copy blocks (BZd*512 planes)

typedef float v2f __attribute__((ext_vector_type(2)));

__device__ __forceinline__ unsigned ordf(float f) {
  unsigned u = __float_as_uint(f);
  return (u & 0x80000000u) ? ~u : (u | 0x80000000u);
}

__device__ __forceinline__ unsigned long long shfl_down_u64(unsigned long long v, int off) {
  unsigned lo = (unsigned)v, hi = (unsigned)(v >> 32);
  lo = __shfl_down(lo, off, 64);
  hi = __shfl_down(hi, off, 64);
  return ((unsigned long long)hi << 32) | lo;
}

// --- K1: inv-norm (blocks 0..255, 4x parallel over c-groups) + mask
//         compaction (blocks 256..259) ---------------------------------------
__global__ void prep_kernel(const float* __restrict__ in, const int* __restrict__ mask,
                            float* __restrict__ inv, int* __restrict__ qcnt,
                            int* __restrict__ kcnt, int* __restrict__ qlist,
                            int* __restrict__ klist, int* __restrict__ srcmap) {
  int bid = blockIdx.x, t = threadIdx.x;
  if (bid < 256) {
    // 64 pixels per block x 4 c-groups of 64 channels
    __shared__ float sred[4][64];
    int p = t & 63, g = t >> 6;
    int idx = bid * 64 + p;                   // [0, 16384); 64 | HW so no b-crossing
    int b = idx >> 12, j = idx & (HW - 1);
    const float* base = in + ((size_t)b * 512 + C2 + g * 64) * HW + j;
    float ss = 0.f;
#pragma unroll 8
    for (int c = 0; c < 64; ++c) { float v = base[(size_t)c * HW]; ss = fmaf(v, v, ss); }
    sred[g][p] = ss;
    __syncthreads();
    if (g == 0) {
      float s0 = ((sred[0][p] + sred[1][p]) + sred[2][p]) + sred[3][p];
      inv[idx] = 1.0f / (sqrtf(s0) + 1e-8f);
    }
  } else {
    int b = bid - 256;
    __shared__ int s[256];
    const int* m = mask + b * HW;
    int base = t * 16;
    int fl = 0, cq = 0;
#pragma unroll
    for (int i = 0; i < 16; ++i) { int f = (m[base + i] >= 1); fl |= f << i; cq += f; }
    s[t] = cq; __syncthreads();
    for (int off = 1; off < 256; off <<= 1) {
      int v = (t >= off) ? s[t - off] : 0;
      __syncthreads(); s[t] += v; __syncthreads();
    }
    int total = s[255];
    int qp = s[t] - cq;
    int kp = base - qp;
    for (int i = 0; i < 16; ++i) {
      int j = base + i;
      if ((fl >> i) & 1) qlist[b * HW + qp++] = j;
      else               klist[b * HW + kp++] = j;
      srcmap[b * HW + j] = -1;
    }
    if (t == 0) { qcnt[b] = total; kcnt[b] = HW - total; }
  }
}

// --- K2: pack normalized keys + un-normalized queries via LDS-staged gather.
__global__ void pack_kernel(const float* __restrict__ in, const float* __restrict__ inv,
                            const int* __restrict__ qcnt, const int* __restrict__ kcnt,
                            const int* __restrict__ qlist, const int* __restrict__ klist,
                            float* __restrict__ kpack, float* __restrict__ qpack) {
  __shared__ float slat[HW];   // 16 KB
  __shared__ float sinv[HW];   // 16 KB
  int t = threadIdx.x;
  int c = blockIdx.x, b = blockIdx.y;
  const float4* lat4 = (const float4*)(in + ((size_t)b * 512 + C2 + c) * HW);
  const float4* inv4 = (const float4*)(inv + (size_t)b * HW);
#pragma unroll
  for (int i = 0; i < 4; ++i) {
    int p = i * 256 + t;
    ((float4*)slat)[p] = lat4[p];
    ((float4*)sinv)[p] = inv4[p];
  }
  int kc = kcnt[b], nq = qcnt[b];
  const int* kl = klist + b * HW;
  const int* ql = qlist + b * HW;
  float* kdst = kpack + (size_t)(b * C2 + c) * HW;
  float* qdst = qpack + (size_t)(b * C2 + c) * HW;
  __syncthreads();
#pragma unroll
  for (int i = 0; i < 4; ++i) {
    int jj = (i * 256 + t) * 4;
    int4 k4 = *(const int4*)(kl + jj);   // entries beyond kc are garbage: guarded
    int4 q4 = *(const int4*)(ql + jj);
    float4 kv, qv;
    kv.x = (jj + 0 < kc) ? slat[k4.x] * sinv[k4.x] : 0.f;
    kv.y = (jj + 1 < kc) ? slat[k4.y] * sinv[k4.y] : 0.f;
    kv.z = (jj + 2 < kc) ? slat[k4.z] * sinv[k4.z] : 0.f;
    kv.w = (jj + 3 < kc) ? slat[k4.w] * sinv[k4.w] : 0.f;
    qv.x = (jj + 0 < nq) ? slat[q4.x] : 0.f;
    qv.y = (jj + 1 < nq) ? slat[q4.y] : 0.f;
    qv.z = (jj + 2 < nq) ? slat[q4.z] : 0.f;
    qv.w = (jj + 3 < nq) ? slat[q4.w] : 0.f;
    *(float4*)(kdst + jj) = kv;
    *(float4*)(qdst + jj) = qv;
  }
}

// --- K3 helpers --------------------------------------------------------------
// Main decode: nt_b = qt_b * s_b with s_b = min(ceil(kc/512), 4); sl in [0,4).
__device__ __forceinline__ void decode_id(unsigned idx,
    int nt0, int nt1, int nt2,
    int q0, int q1, int q2, int q3,
    int k0c, int k1c, int k2c, int k3c,
    int& b, int& sl, int& qtile, int& kc) {
  int qtn;
  b = 0; qtn = q0; kc = k0c;
  if (idx >= (unsigned)nt0) {
    idx -= nt0; b = 1; qtn = q1; kc = k1c;
    if (idx >= (unsigned)nt1) {
      idx -= nt1; b = 2; qtn = q2; kc = k2c;
      if (idx >= (unsigned)nt2) { idx -= nt2; b = 3; qtn = q3; kc = k3c; }
    }
  }
  sl = (int)(idx / (unsigned)qtn);
  qtile = (int)(idx - (unsigned)sl * (unsigned)qtn);
}

// Overflow decode: ids cover slices 4.. for batches with kc > 2048.
// on_b = qt_b * (ceil(kc/512) - 4 clamped >= 0); sl = 4 + local/qt.
__device__ __forceinline__ void decode_ov(unsigned idx,
    int on0, int on1, int on2,
    int q0, int q1, int q2, int q3,
    int k0c, int k1c, int k2c, int k3c,
    int& b, int& sl, int& qtile, int& kc) {
  int qtn;
  b = 0; qtn = q0; kc = k0c;
  if (idx >= (unsigned)on0) {
    idx -= on0; b = 1; qtn = q1; kc = k1c;
    if (idx >= (unsigned)on1) {
      idx -= on1; b = 2; qtn = q2; kc = k2c;
      if (idx >= (unsigned)on2) { idx -= on2; b = 3; qtn = q3; kc = k3c; }
    }
  }
  sl = 4 + (int)(idx / (unsigned)qtn);
  qtile = (int)(idx - (unsigned)(sl - 4) * (unsigned)qtn);
}

// One work item: TQL queries (qtile*32 + qoff ..) x one 512-key slice.
// Body identical to R8 (VGPR 48 known-good). kpack zero-padded beyond kc;
// kk<kc guards the candidate max -> correct for partial slices.
template <int TQL>
__device__ __forceinline__ void run_item(
    const float* __restrict__ qpack, const float* __restrict__ kpack,
    unsigned long long* __restrict__ partials,
    unsigned long long (*red)[TQ],
    int b, int sl, int qtile, int qoff, int kc,
    int t, int lane, int wid) {
  int qstart = (qtile << 5) + qoff;
  int kbase = (sl << 9) + (t << 1);   // this thread's 2 keys

  // wave-uniform query base -> scalar loads (SGPR broadcast operands)
  const float* qb = qpack + ((size_t)b * C2) * HW + qstart;
  const float* kcol = kpack + ((size_t)b * C2) * HW + kbase;

  v2f acc[NK][TQL / 2];
#pragma unroll
  for (int r = 0; r < NK; ++r)
#pragma unroll
    for (int q = 0; q < TQL / 2; ++q) acc[r][q] = (v2f){0.f, 0.f};

  // rotating depth-2 prefetch of the key float2 (stride HW floats per c)
  float2 k0 = *(const float2*)(kcol);
  float2 k1 = *(const float2*)(kcol + HW);
#pragma unroll 2
  for (int c = 0; c < C2; ++c) {
    float2 kq = k0;
    k0 = k1;
    int cp = c + 2; if (cp > C2 - 1) cp = C2 - 1;
    k1 = *(const float2*)(kcol + (size_t)cp * HW);
    v2f kv2[NK];
    kv2[0] = (v2f){kq.x, kq.x};
    kv2[1] = (v2f){kq.y, kq.y};
    const v2f* qc2 = (const v2f*)(qb + (size_t)c * HW);   // uniform address
#pragma unroll
    for (int i = 0; i < TQL / 2; ++i) {
      v2f qv = qc2[i];                        // s_load pair -> SGPR
#pragma unroll
      for (int r = 0; r < NK; ++r)
        acc[r][i] = __builtin_elementwise_fma(kv2[r], qv, acc[r][i]);
    }
  }

  // per-q reduction: wave shfl, then cross-wave via LDS
#pragma unroll
  for (int q = 0; q < TQL; ++q) {
    unsigned long long v = 0ull;
#pragma unroll
    for (int r = 0; r < NK; ++r) {
      int kk = kbase + r;
      if (kk < kc) {
        float a = (q & 1) ? acc[r][q >> 1].y : acc[r][q >> 1].x;
        unsigned long long pk =
            ((unsigned long long)ordf(a) << 32) | (unsigned)(0xFFFFFFFFu - (unsigned)kk);
        if (pk > v) v = pk;
      }
    }
#pragma unroll
    for (int off = 32; off >= 1; off >>= 1) {
      unsigned long long o = shfl_down_u64(v, off);
      if (o > v) v = o;
    }
    if (lane == 0) red[wid][q] = v;
  }
  __syncthreads();
  if (t < TQL) {
    unsigned long long v = red[0][t];
#pragma unroll
    for (int ww = 1; ww < 4; ++ww) if (red[ww][t] > v) v = red[ww][t];
    partials[(((size_t)b * NSL_MAX + sl) * QT_MAX + qtile) * TQ + qoff + t] = v;
  }
  __syncthreads();
}

// --- K3: fused GEMM + per-slice argmax. Work-id space = [main (ns capped 4)]
// ++ [overflow slices 4..7] in ONE loop / one run_item<32> call site; then
// main remainder split 4-ways along q; then appended passthrough-copy blocks.
__global__ __launch_bounds__(BT, 4) void argmax_pass1(
    const float* __restrict__ qpack, const float* __restrict__ kpack,
    const int* __restrict__ qcnt, const int* __restrict__ kcnt,
    unsigned long long* __restrict__ partials,
    const float* __restrict__ in, float* __restrict__ out) {
  int t = threadIdx.x;
  if (blockIdx.x >= P1_GRID) {
    // passthrough copy: one (b,c) plane per block, c in [0,512)
    int bid2 = blockIdx.x - P1_GRID;
    int b = bid2 >> 9, c = bid2 & 511;
    const float4* src = (const float4*)(in + ((size_t)b * 512 + c) * HW);
    float4* dst = (float4*)(out + ((size_t)b * 768 + c) * HW);
#pragma unroll
    for (int i = 0; i < 4; ++i) dst[i * 256 + t] = src[i * 256 + t];
    return;
  }

  // per-batch work-item counts (uniform -> scalar)
  int k0c = kcnt[0], k1c = kcnt[1], k2c = kcnt[2], k3c = kcnt[3];
  int st0 = (k0c + SLK - 1) >> 9, st1 = (k1c + SLK - 1) >> 9;
  int st2 = (k2c + SLK - 1) >> 9, st3 = (k3c + SLK - 1) >> 9;
  int s0 = st0 > 4 ? 4 : st0, s1 = st1 > 4 ? 4 : st1;
  int s2 = st2 > 4 ? 4 : st2, s3 = st3 > 4 ? 4 : st3;
  int o0 = st0 - s0, o1 = st1 - s1, o2 = st2 - s2, o3 = st3 - s3;
  int q0 = (qcnt[0] + TQ - 1) >> 5, q1 = (qcnt[1] + TQ - 1) >> 5;
  int q2 = (qcnt[2] + TQ - 1) >> 5, q3 = (qcnt[3] + TQ - 1) >> 5;
  int nt0 = q0 * s0, nt1 = q1 * s1, nt2 = q2 * s2, nt3 = q3 * s3;
  int on0 = q0 * o0, on1 = q1 * o1, on2 = q2 * o2, on3 = q3 * o3;
  unsigned total = (unsigned)(nt0 + nt1 + nt2 + nt3);
  unsigned total_ov = (unsigned)(on0 + on1 + on2 + on3);
  unsigned S = P1_GRID;
  unsigned F = total / S;
  unsigned fullN = (F == 0) ? total : F * S;   // total<S: all items full-size
  unsigned R = total - fullN;

  int lane = t & 63, wid = t >> 6;
  __shared__ unsigned long long red[4][TQ];

  // phase 1: full-size items, then overflow items -- same call site.
  // Blocks with bid >= total grab overflow DURING the main round.
  for (unsigned w = blockIdx.x; w < fullN + total_ov; w += S) {
    int b, sl, qtile, kc;
    if (w < fullN)
      decode_id(w, nt0, nt1, nt2, q0, q1, q2, q3, k0c, k1c, k2c, k3c, b, sl, qtile, kc);
    else
      decode_ov(w - fullN, on0, on1, on2, q0, q1, q2, q3, k0c, k1c, k2c, k3c, b, sl, qtile, kc);
    run_item<TQ>(qpack, kpack, partials, red, b, sl, qtile, 0, kc, t, lane, wid);
  }
  // phase 2: main remainder split 4-ways along q (quarter-duration round)
  for (unsigned qi = blockIdx.x; qi < 4u * R; qi += S) {
    unsigned id = fullN + (qi >> 2);
    int sub = (int)(qi & 3u);
    int b, sl, qtile, kc;
    decode_id(id, nt0, nt1, nt2, q0, q1, q2, q3, k0c, k1c, k2c, k3c, b, sl, qtile, kc);
    run_item<8>(qpack, kpack, partials, red, b, sl, qtile, sub * 8, kc, t, lane, wid);
  }
}

// --- K4: reduce slices -> srcmap (reads all true slices incl. overflow) -----
__global__ void argmax_pass2(const unsigned long long* __restrict__ partials,
                             const int* __restrict__ qcnt, const int* __restrict__ kcnt,
                             const int* __restrict__ qlist, const int* __restrict__ klist,
                             int* __restrict__ srcmap) {
  int idx = blockIdx.x * 256 + threadIdx.x;  // [0, 16384)
  int b = idx >> 12, qpos = idx & (HW - 1);
  if (qpos >= qcnt[b]) return;
  int kc = kcnt[b];
  int ns = (kc + SLK - 1) >> 9;
  int qtile = qpos >> 5, q = qpos & (TQ - 1);
  unsigned long long v = 0ull;
  for (int s = 0; s < ns; ++s) {
    unsigned long long p = partials[(((size_t)b * NSL_MAX + s) * QT_MAX + qtile) * TQ + q];
    if (p > v) v = p;
  }
  if (!v) return;
  int kk = (int)(0xFFFFFFFFu - (unsigned)(v & 0xFFFFFFFFull));
  srcmap[b * HW + qlist[b * HW + qpos]] = klist[b * HW + kk];
}

// --- K5: gather-only: one block per (b,c<256): stage former plane in LDS,
// gather via srcmap (passthrough already written by pass1's copy blocks) ------
__global__ void out_kernel(const float* __restrict__ in, const int* __restrict__ srcmap,
                           float* __restrict__ out) {
  __shared__ float srow[HW];   // 16 KB
  int bid = blockIdx.x;
  int b = bid >> 8, c = bid & 255;
  int t = threadIdx.x;
  const float4* src = (const float4*)(in + ((size_t)b * 512 + c) * HW);
#pragma unroll
  for (int i = 0; i < 4; ++i) ((float4*)srow)[i * 256 + t] = src[i * 256 + t];
  __syncthreads();
  const int* sm = srcmap + b * HW;
  float4* dst2 = (float4*)(out + ((size_t)b * 768 + 512 + c) * HW);
#pragma unroll
  for (int i = 0; i < 4; ++i) {
    int p = i * 256 + t;
    int j0 = p * 4;
    int4 s4 = *(const int4*)(sm + j0);
    float4 o;
    o.x = (s4.x >= 0) ? srow[s4.x] : 0.f;
    o.y = (s4.y >= 0) ? srow[s4.y] : 0.f;
    o.z = (s4.z >= 0) ? srow[s4.z] : 0.f;
    o.w = (s4.w >= 0) ? srow[s4.w] : 0.f;
    dst2[p] = o;
  }
}

extern "C" void kernel_launch(void* const* d_in, const int* in_sizes, int n_in,
                              void* d_out, int out_size, void* d_ws, size_t ws_size,
                              hipStream_t stream) {
  const float* in = (const float*)d_in[0];
  const int* mask = (const int*)d_in[1];
  float* out = (float*)d_out;

  // workspace layout (~35 MB)
  unsigned long long* partials = (unsigned long long*)d_ws;                    // 4*8*128*32 u64 = 1 MB
  float* kpack = (float*)(partials + (size_t)BZd * NSL_MAX * QT_MAX * TQ);     // 16.8 MB
  float* qpack = kpack + (size_t)BZd * C2 * HW;                                 // 16.8 MB
  float* inv = qpack + (size_t)BZd * C2 * HW;                                   // 64 KB
  int* qlist = (int*)(inv + BZd * HW);                                          // 64 KB
  int* klist = qlist + BZd * HW;                                                // 64 KB
  int* srcmap = klist + BZd * HW;                                               // 64 KB
  int* qcnt = srcmap + BZd * HW;                                                // 16 B
  int* kcnt = qcnt + BZd;                                                       // 16 B

  hipLaunchKernelGGL(prep_kernel, dim3(256 + BZd), dim3(256), 0, stream,
                     in, mask, inv, qcnt, kcnt, qlist, klist, srcmap);
  hipLaunchKernelGGL(pack_kernel, dim3(C2, BZd), dim3(256), 0, stream,
                     in, inv, qcnt, kcnt, qlist, klist, kpack, qpack);
  hipLaunchKernelGGL(argmax_pass1, dim3(P1_GRID + CP_GRID), dim3(BT), 0, stream,
                     qpack, kpack, qcnt, kcnt, partials, in, out);
  hipLaunchKernelGGL(argmax_pass2, dim3(BZd * HW / 256), dim3(256), 0, stream,
                     partials, qcnt, kcnt, qlist, klist, srcmap);
  hipLaunchKernelGGL(out_kernel, dim3(BZd * 256), dim3(256), 0, stream,
                     in, srcmap, out);
}

// Round 12
// 216.970 us; speedup vs baseline: 1.2755x; 1.2755x over previous
//
#include <hip/hip_runtime.h>

// InnerShiftTriple: bz=4, c=512 (c2=256), h=w=64 (hw=4096), fp32 in/out, int32 mask.
// out = concat([former, latter, shifted]); shifted[i] = former[argmax_j sim(i,j)]
// for masked i over non-masked keys j, cosine sim of "latter" features.
// Argmax invariant to query normalization -> only keys normalized.
//
// Pass1: TQ=32 x 512-key items, 4-wave blocks, launch_bounds(256,4), static
// schedule + q-split remainder; fused passthrough copy (WRITE 33MB == copy).
// Tail model (R4/R8/R11-consistent): tail cost = SERIAL latency of one TQL=8
// item: 256 c-iters x ~220cyc SMEM-queue drain (s_load is out-of-order ->
// any use forces lgkmcnt(0)) ~= 58-63us, independent of item count.
// R11 slice-capping deleted nothing (C2 loop cost is key-count-independent).
// THIS ROUND: tail q via LDS -- stage 8q x 256c (8KB) once per sub-item,
// per-iter ds_read broadcast (IN-ORDER -> fine lgkmcnt, no drain); k keeps
// the main path's depth-2 rotation (R10's kpre[8] = +16 VGPR was the
// occupancy killer; avoided). Tail footprint ~36 VGPR < main's 48 -> shared
// kernel allocation should stay 48 (go/no-go counter). Bit-identical argmax.

#define HW 4096
#define C2 256
#define BZd 4
#define TQ 32         // queries per full work item (SGPR-broadcast)
#define NK 2          // keys per thread (one float2)
#define BT 256        // pass1 block = 4 waves; block covers BT*NK = 512 keys
#define SLK 512       // keys per slice
#define NSL_MAX 8     // up to 8 slices of 512 keys
#define QT_MAX 128    // HW/TQ
#define P1_GRID 1024  // exactly the resident capacity at 4 blocks/CU
#define CP_GRID 2048  // appended passthrough-copy blocks (BZd*512 planes)

typedef float v2f __attribute__((ext_vector_type(2)));

__device__ __forceinline__ unsigned ordf(float f) {
  unsigned u = __float_as_uint(f);
  return (u & 0x80000000u) ? ~u : (u | 0x80000000u);
}

__device__ __forceinline__ unsigned long long shfl_down_u64(unsigned long long v, int off) {
  unsigned lo = (unsigned)v, hi = (unsigned)(v >> 32);
  lo = __shfl_down(lo, off, 64);
  hi = __shfl_down(hi, off, 64);
  return ((unsigned long long)hi << 32) | lo;
}

// --- K1: inv-norm (blocks 0..255, 4x parallel over c-groups) + mask
//         compaction (blocks 256..259) ---------------------------------------
__global__ void prep_kernel(const float* __restrict__ in, const int* __restrict__ mask,
                            float* __restrict__ inv, int* __restrict__ qcnt,
                            int* __restrict__ kcnt, int* __restrict__ qlist,
                            int* __restrict__ klist, int* __restrict__ srcmap) {
  int bid = blockIdx.x, t = threadIdx.x;
  if (bid < 256) {
    // 64 pixels per block x 4 c-groups of 64 channels
    __shared__ float sred[4][64];
    int p = t & 63, g = t >> 6;
    int idx = bid * 64 + p;                   // [0, 16384); 64 | HW so no b-crossing
    int b = idx >> 12, j = idx & (HW - 1);
    const float* base = in + ((size_t)b * 512 + C2 + g * 64) * HW + j;
    float ss = 0.f;
#pragma unroll 8
    for (int c = 0; c < 64; ++c) { float v = base[(size_t)c * HW]; ss = fmaf(v, v, ss); }
    sred[g][p] = ss;
    __syncthreads();
    if (g == 0) {
      float s0 = ((sred[0][p] + sred[1][p]) + sred[2][p]) + sred[3][p];
      inv[idx] = 1.0f / (sqrtf(s0) + 1e-8f);
    }
  } else {
    int b = bid - 256;
    __shared__ int s[256];
    const int* m = mask + b * HW;
    int base = t * 16;
    int fl = 0, cq = 0;
#pragma unroll
    for (int i = 0; i < 16; ++i) { int f = (m[base + i] >= 1); fl |= f << i; cq += f; }
    s[t] = cq; __syncthreads();
    for (int off = 1; off < 256; off <<= 1) {
      int v = (t >= off) ? s[t - off] : 0;
      __syncthreads(); s[t] += v; __syncthreads();
    }
    int total = s[255];
    int qp = s[t] - cq;
    int kp = base - qp;
    for (int i = 0; i < 16; ++i) {
      int j = base + i;
      if ((fl >> i) & 1) qlist[b * HW + qp++] = j;
      else               klist[b * HW + kp++] = j;
      srcmap[b * HW + j] = -1;
    }
    if (t == 0) { qcnt[b] = total; kcnt[b] = HW - total; }
  }
}

// --- K2: pack normalized keys + un-normalized queries via LDS-staged gather.
__global__ void pack_kernel(const float* __restrict__ in, const float* __restrict__ inv,
                            const int* __restrict__ qcnt, const int* __restrict__ kcnt,
                            const int* __restrict__ qlist, const int* __restrict__ klist,
                            float* __restrict__ kpack, float* __restrict__ qpack) {
  __shared__ float slat[HW];   // 16 KB
  __shared__ float sinv[HW];   // 16 KB
  int t = threadIdx.x;
  int c = blockIdx.x, b = blockIdx.y;
  const float4* lat4 = (const float4*)(in + ((size_t)b * 512 + C2 + c) * HW);
  const float4* inv4 = (const float4*)(inv + (size_t)b * HW);
#pragma unroll
  for (int i = 0; i < 4; ++i) {
    int p = i * 256 + t;
    ((float4*)slat)[p] = lat4[p];
    ((float4*)sinv)[p] = inv4[p];
  }
  int kc = kcnt[b], nq = qcnt[b];
  const int* kl = klist + b * HW;
  const int* ql = qlist + b * HW;
  float* kdst = kpack + (size_t)(b * C2 + c) * HW;
  float* qdst = qpack + (size_t)(b * C2 + c) * HW;
  __syncthreads();
#pragma unroll
  for (int i = 0; i < 4; ++i) {
    int jj = (i * 256 + t) * 4;
    int4 k4 = *(const int4*)(kl + jj);   // entries beyond kc are garbage: guarded
    int4 q4 = *(const int4*)(ql + jj);
    float4 kv, qv;
    kv.x = (jj + 0 < kc) ? slat[k4.x] * sinv[k4.x] : 0.f;
    kv.y = (jj + 1 < kc) ? slat[k4.y] * sinv[k4.y] : 0.f;
    kv.z = (jj + 2 < kc) ? slat[k4.z] * sinv[k4.z] : 0.f;
    kv.w = (jj + 3 < kc) ? slat[k4.w] * sinv[k4.w] : 0.f;
    qv.x = (jj + 0 < nq) ? slat[q4.x] : 0.f;
    qv.y = (jj + 1 < nq) ? slat[q4.y] : 0.f;
    qv.z = (jj + 2 < nq) ? slat[q4.z] : 0.f;
    qv.w = (jj + 3 < nq) ? slat[q4.w] : 0.f;
    *(float4*)(kdst + jj) = kv;
    *(float4*)(qdst + jj) = qv;
  }
}

// --- K3 helpers --------------------------------------------------------------
__device__ __forceinline__ void decode_id(unsigned idx,
    int nt0, int nt1, int nt2,
    int q0, int q1, int q2, int q3,
    int k0c, int k1c, int k2c, int k3c,
    int& b, int& sl, int& qtile, int& kc) {
  int qtn;
  b = 0; qtn = q0; kc = k0c;
  if (idx >= (unsigned)nt0) {
    idx -= nt0; b = 1; qtn = q1; kc = k1c;
    if (idx >= (unsigned)nt1) {
      idx -= nt1; b = 2; qtn = q2; kc = k2c;
      if (idx >= (unsigned)nt2) { idx -= nt2; b = 3; qtn = q3; kc = k3c; }
    }
  }
  sl = (int)(idx / (unsigned)qtn);
  qtile = (int)(idx - (unsigned)sl * (unsigned)qtn);
}

// Full item (phase 1): 32q x 512k, depth-2 k-prefetch, SGPR q. R8 body.
__device__ __forceinline__ void run_item32(
    const float* __restrict__ qpack, const float* __restrict__ kpack,
    unsigned long long* __restrict__ partials,
    unsigned long long (*red)[TQ],
    int b, int sl, int qtile, int kc,
    int t, int lane, int wid) {
  int qstart = qtile << 5;
  int kbase = (sl << 9) + (t << 1);   // this thread's 2 keys

  const float* qb = qpack + ((size_t)b * C2) * HW + qstart;
  const float* kcol = kpack + ((size_t)b * C2) * HW + kbase;

  v2f acc[NK][TQ / 2];
#pragma unroll
  for (int r = 0; r < NK; ++r)
#pragma unroll
    for (int q = 0; q < TQ / 2; ++q) acc[r][q] = (v2f){0.f, 0.f};

  float2 k0 = *(const float2*)(kcol);
  float2 k1 = *(const float2*)(kcol + HW);
#pragma unroll 2
  for (int c = 0; c < C2; ++c) {
    float2 kq = k0;
    k0 = k1;
    int cp = c + 2; if (cp > C2 - 1) cp = C2 - 1;
    k1 = *(const float2*)(kcol + (size_t)cp * HW);
    v2f kv2[NK];
    kv2[0] = (v2f){kq.x, kq.x};
    kv2[1] = (v2f){kq.y, kq.y};
    const v2f* qc2 = (const v2f*)(qb + (size_t)c * HW);   // uniform address
#pragma unroll
    for (int i = 0; i < TQ / 2; ++i) {
      v2f qv = qc2[i];                        // s_load pair -> SGPR
#pragma unroll
      for (int r = 0; r < NK; ++r)
        acc[r][i] = __builtin_elementwise_fma(kv2[r], qv, acc[r][i]);
    }
  }

#pragma unroll
  for (int q = 0; q < TQ; ++q) {
    unsigned long long v = 0ull;
#pragma unroll
    for (int r = 0; r < NK; ++r) {
      int kk = kbase + r;
      if (kk < kc) {
        float a = (q & 1) ? acc[r][q >> 1].y : acc[r][q >> 1].x;
        unsigned long long pk =
            ((unsigned long long)ordf(a) << 32) | (unsigned)(0xFFFFFFFFu - (unsigned)kk);
        if (pk > v) v = pk;
      }
    }
#pragma unroll
    for (int off = 32; off >= 1; off >>= 1) {
      unsigned long long o = shfl_down_u64(v, off);
      if (o > v) v = o;
    }
    if (lane == 0) red[wid][q] = v;
  }
  __syncthreads();
  if (t < TQ) {
    unsigned long long v = red[0][t];
#pragma unroll
    for (int ww = 1; ww < 4; ++ww) if (red[ww][t] > v) v = red[ww][t];
    partials[(((size_t)b * NSL_MAX + sl) * QT_MAX + qtile) * TQ + t] = v;
  }
  __syncthreads();
}

// Tail sub-item: 8q x 512k. q staged in LDS once (8KB, conflict-free linear
// map), per-iter 4 broadcast v2f ds_reads (IN-ORDER -> no SMEM-queue drain);
// k keeps depth-2 VMEM rotation (no kpre[8] VGPR bloat). Same fmaf chain.
__device__ __forceinline__ void run_item_tail(
    const float* __restrict__ qpack, const float* __restrict__ kpack,
    unsigned long long* __restrict__ partials,
    unsigned long long (*red)[TQ], float (*sQ)[8],
    int b, int sl, int qtile, int qoff, int kc,
    int t, int lane, int wid) {
  int qstart = (qtile << 5) + qoff;
  int kbase = (sl << 9) + (t << 1);

  const float* qb = qpack + ((size_t)b * C2) * HW + qstart;
  const float* kcol = kpack + ((size_t)b * C2) * HW + kbase;

  // stage q[256 c][8 q] -> LDS. thread t -> (c = t>>3 + 32r, qi = t&7):
  // consecutive lanes write consecutive floats -> conflict-free.
  {
    int qi = t & 7, c0 = t >> 3;
#pragma unroll
    for (int r = 0; r < 8; ++r)
      sQ[c0 + r * 32][qi] = qb[(size_t)(c0 + r * 32) * HW + qi];
  }
  __syncthreads();

  v2f acc[NK][4];
#pragma unroll
  for (int r = 0; r < NK; ++r)
#pragma unroll
    for (int q = 0; q < 4; ++q) acc[r][q] = (v2f){0.f, 0.f};

  float2 k0 = *(const float2*)(kcol);
  float2 k1 = *(const float2*)(kcol + HW);
#pragma unroll 2
  for (int c = 0; c < C2; ++c) {
    float2 kq = k0;
    k0 = k1;
    int cp = c + 2; if (cp > C2 - 1) cp = C2 - 1;
    k1 = *(const float2*)(kcol + (size_t)cp * HW);
    v2f kv0 = (v2f){kq.x, kq.x};
    v2f kv1 = (v2f){kq.y, kq.y};
    const v2f* qrow = (const v2f*)&sQ[c][0];   // same addr all lanes: broadcast
#pragma unroll
    for (int i = 0; i < 4; ++i) {
      v2f qv = qrow[i];                        // ds_read_b64, in-order
      acc[0][i] = __builtin_elementwise_fma(kv0, qv, acc[0][i]);
      acc[1][i] = __builtin_elementwise_fma(kv1, qv, acc[1][i]);
    }
  }

#pragma unroll
  for (int q = 0; q < 8; ++q) {
    unsigned long long v = 0ull;
#pragma unroll
    for (int r = 0; r < NK; ++r) {
      int kk = kbase + r;
      if (kk < kc) {
        float a = (q & 1) ? acc[r][q >> 1].y : acc[r][q >> 1].x;
        unsigned long long pk =
            ((unsigned long long)ordf(a) << 32) | (unsigned)(0xFFFFFFFFu - (unsigned)kk);
        if (pk > v) v = pk;
      }
    }
#pragma unroll
    for (int off = 32; off >= 1; off >>= 1) {
      unsigned long long o = shfl_down_u64(v, off);
      if (o > v) v = o;
    }
    if (lane == 0) red[wid][q] = v;
  }
  __syncthreads();
  if (t < 8) {
    unsigned long long v = red[0][t];
#pragma unroll
    for (int ww = 1; ww < 4; ++ww) if (red[ww][t] > v) v = red[ww][t];
    partials[(((size_t)b * NSL_MAX + sl) * QT_MAX + qtile) * TQ + qoff + t] = v;
  }
  __syncthreads();
}

// --- K3: fused GEMM + per-slice argmax over dense (b,sl,qtile) work items,
// plus appended passthrough-copy blocks (fill the remainder-tail slots) ------
__global__ __launch_bounds__(BT, 4) void argmax_pass1(
    const float* __restrict__ qpack, const float* __restrict__ kpack,
    const int* __restrict__ qcnt, const int* __restrict__ kcnt,
    unsigned long long* __restrict__ partials,
    const float* __restrict__ in, float* __restrict__ out) {
  int t = threadIdx.x;
  if (blockIdx.x >= P1_GRID) {
    // passthrough copy: one (b,c) plane per block, c in [0,512)
    int bid2 = blockIdx.x - P1_GRID;
    int b = bid2 >> 9, c = bid2 & 511;
    const float4* src = (const float4*)(in + ((size_t)b * 512 + c) * HW);
    float4* dst = (float4*)(out + ((size_t)b * 768 + c) * HW);
#pragma unroll
    for (int i = 0; i < 4; ++i) dst[i * 256 + t] = src[i * 256 + t];
    return;
  }

  // per-batch work-item counts (uniform -> scalar)
  int k0c = kcnt[0], k1c = kcnt[1], k2c = kcnt[2], k3c = kcnt[3];
  int s0 = (k0c + SLK - 1) >> 9, s1 = (k1c + SLK - 1) >> 9;
  int s2 = (k2c + SLK - 1) >> 9, s3 = (k3c + SLK - 1) >> 9;
  int q0 = (qcnt[0] + TQ - 1) >> 5, q1 = (qcnt[1] + TQ - 1) >> 5;
  int q2 = (qcnt[2] + TQ - 1) >> 5, q3 = (qcnt[3] + TQ - 1) >> 5;
  int nt0 = q0 * s0, nt1 = q1 * s1, nt2 = q2 * s2, nt3 = q3 * s3;
  unsigned total = (unsigned)(nt0 + nt1 + nt2 + nt3);
  unsigned S = P1_GRID;
  unsigned F = total / S;
  unsigned fullN = F * S;
  unsigned R = total - fullN;

  int lane = t & 63, wid = t >> 6;
  __shared__ unsigned long long red[4][TQ];
  __shared__ float sQ[C2][8];   // tail q stage (8 KB)

  // phase 1: full-size items (all S slots busy for F rounds)
  for (unsigned w = blockIdx.x; w < fullN; w += S) {
    int b, sl, qtile, kc;
    decode_id(w, nt0, nt1, nt2, q0, q1, q2, q3, k0c, k1c, k2c, k3c, b, sl, qtile, kc);
    run_item32(qpack, kpack, partials, red, b, sl, qtile, kc, t, lane, wid);
  }
  // phase 2: remainder items split 4-ways along q; LDS-q tail (no SMEM drain)
  for (unsigned qi = blockIdx.x; qi < 4u * R; qi += S) {
    unsigned id = fullN + (qi >> 2);
    int sub = (int)(qi & 3u);
    int b, sl, qtile, kc;
    decode_id(id, nt0, nt1, nt2, q0, q1, q2, q3, k0c, k1c, k2c, k3c, b, sl, qtile, kc);
    run_item_tail(qpack, kpack, partials, red, sQ, b, sl, qtile, sub * 8, kc, t, lane, wid);
  }
}

// --- K4: reduce slices -> srcmap --------------------------------------------
__global__ void argmax_pass2(const unsigned long long* __restrict__ partials,
                             const int* __restrict__ qcnt, const int* __restrict__ kcnt,
                             const int* __restrict__ qlist, const int* __restrict__ klist,
                             int* __restrict__ srcmap) {
  int idx = blockIdx.x * 256 + threadIdx.x;  // [0, 16384)
  int b = idx >> 12, qpos = idx & (HW - 1);
  if (qpos >= qcnt[b]) return;
  int kc = kcnt[b];
  int ns = (kc + SLK - 1) >> 9;
  int qtile = qpos >> 5, q = qpos & (TQ - 1);
  unsigned long long v = 0ull;
  for (int s = 0; s < ns; ++s) {
    unsigned long long p = partials[(((size_t)b * NSL_MAX + s) * QT_MAX + qtile) * TQ + q];
    if (p > v) v = p;
  }
  if (!v) return;
  int kk = (int)(0xFFFFFFFFu - (unsigned)(v & 0xFFFFFFFFull));
  srcmap[b * HW + qlist[b * HW + qpos]] = klist[b * HW + kk];
}

// --- K5: gather-only: one block per (b,c<256): stage former plane in LDS,
// gather via srcmap (passthrough already written by pass1's copy blocks) ------
__global__ void out_kernel(const float* __restrict__ in, const int* __restrict__ srcmap,
                           float* __restrict__ out) {
  __shared__ float srow[HW];   // 16 KB
  int bid = blockIdx.x;
  int b = bid >> 8, c = bid & 255;
  int t = threadIdx.x;
  const float4* src = (const float4*)(in + ((size_t)b * 512 + c) * HW);
#pragma unroll
  for (int i = 0; i < 4; ++i) ((float4*)srow)[i * 256 + t] = src[i * 256 + t];
  __syncthreads();
  const int* sm = srcmap + b * HW;
  float4* dst2 = (float4*)(out + ((size_t)b * 768 + 512 + c) * HW);
#pragma unroll
  for (int i = 0; i < 4; ++i) {
    int p = i * 256 + t;
    int j0 = p * 4;
    int4 s4 = *(const int4*)(sm + j0);
    float4 o;
    o.x = (s4.x >= 0) ? srow[s4.x] : 0.f;
    o.y = (s4.y >= 0) ? srow[s4.y] : 0.f;
    o.z = (s4.z >= 0) ? srow[s4.z] : 0.f;
    o.w = (s4.w >= 0) ? srow[s4.w] : 0.f;
    dst2[p] = o;
  }
}

extern "C" void kernel_launch(void* const* d_in, const int* in_sizes, int n_in,
                              void* d_out, int out_size, void* d_ws, size_t ws_size,
                              hipStream_t stream) {
  const float* in = (const float*)d_in[0];
  const int* mask = (const int*)d_in[1];
  float* out = (float*)d_out;

  // workspace layout (~35 MB)
  unsigned long long* partials = (unsigned long long*)d_ws;                    // 4*8*128*32 u64 = 1 MB
  float* kpack = (float*)(partials + (size_t)BZd * NSL_MAX * QT_MAX * TQ);     // 16.8 MB
  float* qpack = kpack + (size_t)BZd * C2 * HW;                                 // 16.8 MB
  float* inv = qpack + (size_t)BZd * C2 * HW;                                   // 64 KB
  int* qlist = (int*)(inv + BZd * HW);                                          // 64 KB
  int* klist = qlist + BZd * HW;                                                // 64 KB
  int* srcmap = klist + BZd * HW;                                               // 64 KB
  int* qcnt = srcmap + BZd * HW;                                                // 16 B
  int* kcnt = qcnt + BZd;                                                       // 16 B

  hipLaunchKernelGGL(prep_kernel, dim3(256 + BZd), dim3(256), 0, stream,
                     in, mask, inv, qcnt, kcnt, qlist, klist, srcmap);
  hipLaunchKernelGGL(pack_kernel, dim3(C2, BZd), dim3(256), 0, stream,
                     in, inv, qcnt, kcnt, qlist, klist, kpack, qpack);
  hipLaunchKernelGGL(argmax_pass1, dim3(P1_GRID + CP_GRID), dim3(BT), 0, stream,
                     qpack, kpack, qcnt, kcnt, partials, in, out);
  hipLaunchKernelGGL(argmax_pass2, dim3(BZd * HW / 256), dim3(256), 0, stream,
                     partials, qcnt, kcnt, qlist, klist, srcmap);
  hipLaunchKernelGGL(out_kernel, dim3(BZd * 256), dim3(256), 0, stream,
                     in, srcmap, out);
}